// Round 5
// baseline (103.114 us; speedup 1.0000x reference)
//
#include <hip/hip_runtime.h>
#include <math.h>

#define V 128000
#define H 1024

typedef float f32x4 __attribute__((ext_vector_type(4)));

#define ROWS_PER_BLK 16
#define NBLK3 (V / ROWS_PER_BLK) // 8000 logits blocks -> 8000 (max,sum) partials

// ws layout (float offsets): partials only
// [0 .. 2*NBLK3): interleaved (max, sumexp) per logits block

// Contiguous head of w_out uses cacheable loads, tail uses non-temporal
// (proven-neutral-or-better R2 config; L3 residency gives no big win).
#define R_CACHED 48000

__device__ __forceinline__ float wave_reduce_sum(float v) {
#pragma unroll
    for (int off = 32; off > 0; off >>= 1)
        v += __shfl_xor(v, off, 64);
    return v;
}

// Kernel 1: fused gates + combine. One block per hidden element k.
// 6 waves/block: wave w computes dot #w of {i_r,i_z,i_n,h_r,h_z,h_n}(k).
// Thread 0 then applies the GRU gate math and writes h_new[k] = d_out[V+k].
__global__ __launch_bounds__(384) void k_gates_combine(
    const int* __restrict__ token_p, const float* __restrict__ hidden,
    const float* __restrict__ emb,
    const float* __restrict__ w_ih, const float* __restrict__ w_hh,
    const float* __restrict__ b_ih, const float* __restrict__ b_hh,
    float* __restrict__ d_out)
{
    __shared__ float g[6];
    const int k    = blockIdx.x;        // 0..H-1
    const int wave = threadIdx.x >> 6;  // 0..5
    const int lane = threadIdx.x & 63;

    const float* w;
    const float* vec;
    float bias;
    if (wave < 3) {
        const int row = wave * H + k;
        w    = w_ih + (size_t)row * H;
        vec  = emb + (size_t)token_p[0] * H;  // low 32 bits fine for i32/i64 LE
        bias = b_ih[row];
    } else {
        const int row = (wave - 3) * H + k;
        w    = w_hh + (size_t)row * H;
        vec  = hidden;
        bias = b_hh[row];
    }

    const f32x4* w4 = (const f32x4*)w;
    const f32x4* v4 = (const f32x4*)vec;
    float acc = 0.f;
#pragma unroll
    for (int it = 0; it < 4; ++it) {
        f32x4 a = w4[it * 64 + lane];
        f32x4 b = v4[it * 64 + lane];
        acc = fmaf(a.x, b.x, acc);
        acc = fmaf(a.y, b.y, acc);
        acc = fmaf(a.z, b.z, acc);
        acc = fmaf(a.w, b.w, acc);
    }
    acc = wave_reduce_sum(acc);
    if (lane == 0) g[wave] = acc + bias;
    __syncthreads();

    if (threadIdx.x == 0) {
        const float r = 1.f / (1.f + expf(-(g[0] + g[3])));
        const float z = 1.f / (1.f + expf(-(g[1] + g[4])));
        const float n = tanhf(g[2] + r * g[5]);
        d_out[V + k] = (1.f - z) * n + z * hidden[k];
    }
}

// Kernel 2: logits[row] = dot(w_out[row], h_new) + b_out[row]
// R2-proven config: 4 waves/block, 4 rows/wave, 4 independent accumulators;
// cached contiguous head, non-temporal tail. Emits per-block (max, sumexp).
__global__ __launch_bounds__(256) void k_logits(
    const float* __restrict__ w_out, const float* __restrict__ b_out,
    float* __restrict__ d_out, float* __restrict__ ws)
{
    __shared__ float sl[ROWS_PER_BLK];
    const int wave = threadIdx.x >> 6;
    const int lane = threadIdx.x & 63;

    // preload h_new (4 KB, cache-hot) into registers, reused across rows
    const f32x4* h4p = (const f32x4*)(d_out + V);
    f32x4 h4[4];
#pragma unroll
    for (int it = 0; it < 4; ++it) h4[it] = h4p[it * 64 + lane];

    const int base_row = blockIdx.x * ROWS_PER_BLK + wave * 4;
    float acc[4] = {0.f, 0.f, 0.f, 0.f};

    if (base_row + 3 < R_CACHED) {
#pragma unroll
        for (int i = 0; i < 4; ++i) {
            const f32x4* w4 = (const f32x4*)(w_out + (size_t)(base_row + i) * H);
#pragma unroll
            for (int it = 0; it < 4; ++it) {
                f32x4 a = w4[it * 64 + lane];
                acc[i] = fmaf(a.x, h4[it].x, acc[i]);
                acc[i] = fmaf(a.y, h4[it].y, acc[i]);
                acc[i] = fmaf(a.z, h4[it].z, acc[i]);
                acc[i] = fmaf(a.w, h4[it].w, acc[i]);
            }
        }
    } else {
#pragma unroll
        for (int i = 0; i < 4; ++i) {
            const f32x4* w4 = (const f32x4*)(w_out + (size_t)(base_row + i) * H);
#pragma unroll
            for (int it = 0; it < 4; ++it) {
                f32x4 a = __builtin_nontemporal_load(w4 + it * 64 + lane);
                acc[i] = fmaf(a.x, h4[it].x, acc[i]);
                acc[i] = fmaf(a.y, h4[it].y, acc[i]);
                acc[i] = fmaf(a.z, h4[it].z, acc[i]);
                acc[i] = fmaf(a.w, h4[it].w, acc[i]);
            }
        }
    }

#pragma unroll
    for (int i = 0; i < 4; ++i) {
        const float r = wave_reduce_sum(acc[i]);
        if (lane == 0) {
            const float l = r + b_out[base_row + i];
            d_out[base_row + i] = l;
            sl[wave * 4 + i] = l;
        }
    }
    __syncthreads();
    if (threadIdx.x == 0) {
        float m = sl[0];
#pragma unroll
        for (int i = 1; i < ROWS_PER_BLK; ++i) m = fmaxf(m, sl[i]);
        float s = 0.f;
#pragma unroll
        for (int i = 0; i < ROWS_PER_BLK; ++i) s += expf(sl[i] - m);
        ws[2 * blockIdx.x]     = m;
        ws[2 * blockIdx.x + 1] = s;
    }
}

// Kernel 3: fused reduce + subtract. Every block redundantly merges the
// 8000 (max,sumexp) partials (64 KB, L2-hot, identical order -> identical C
// in every block), then subtracts C from its float4 slice of the logits.
// Grid: V/4/256 = 125 blocks.
__global__ __launch_bounds__(256) void k_final(
    float* __restrict__ d_out, const float* __restrict__ ws)
{
    __shared__ float sm[256], ss[256];
    __shared__ float sC;
    const int t = threadIdx.x;

    float m = -INFINITY, s = 0.f;
    for (int j = t; j < NBLK3; j += 256) {
        const float m2 = ws[2 * j];
        const float s2 = ws[2 * j + 1];
        if (m2 > m) { s = s * expf(m - m2) + s2; m = m2; }
        else        { s += s2 * expf(m2 - m); }
    }
    sm[t] = m; ss[t] = s;
    __syncthreads();
#pragma unroll
    for (int off = 128; off > 0; off >>= 1) {
        if (t < off) {
            const float m2 = sm[t + off], s2 = ss[t + off];
            float mm = sm[t], sc = ss[t];
            if (m2 > mm) { sc = sc * expf(mm - m2) + s2; mm = m2; }
            else         { sc += s2 * expf(m2 - mm); }
            sm[t] = mm; ss[t] = sc;
        }
        __syncthreads();
    }
    if (t == 0) sC = sm[0] + logf(ss[0]);
    __syncthreads();

    const float C = sC;
    f32x4* o4 = (f32x4*)d_out;
    const int i = blockIdx.x * 256 + t;   // 0 .. 31999
    f32x4 v = o4[i];
    v.x -= C; v.y -= C; v.z -= C; v.w -= C;
    o4[i] = v;
}

extern "C" void kernel_launch(void* const* d_in, const int* in_sizes, int n_in,
                              void* d_out_v, int out_size, void* d_ws, size_t ws_size,
                              hipStream_t stream) {
    const int*   token  = (const int*)d_in[0];
    const float* hidden = (const float*)d_in[1];
    const float* emb    = (const float*)d_in[2];
    const float* w_ih   = (const float*)d_in[3];
    const float* w_hh   = (const float*)d_in[4];
    const float* b_ih   = (const float*)d_in[5];
    const float* b_hh   = (const float*)d_in[6];
    const float* w_out  = (const float*)d_in[7];
    const float* b_out  = (const float*)d_in[8];
    float* d_out = (float*)d_out_v;
    float* ws    = (float*)d_ws;

    k_gates_combine<<<H, 384, 0, stream>>>(token, hidden, emb, w_ih, w_hh, b_ih, b_hh, d_out);
    k_logits       <<<NBLK3, 256, 0, stream>>>(w_out, b_out, d_out, ws);
    k_final        <<<V / 4 / 256, 256, 0, stream>>>(d_out, ws);
}